// Round 3
// baseline (173.642 us; speedup 1.0000x reference)
//
#include <hip/hip_runtime.h>
#include <hip/hip_bf16.h>

// NT-Xent loss, N=4096, D=256, fp32 in, fp32 scalar out.
// loss = mean_i [ log( sum_{j != i} exp(2*cos_ij) ) - 2*cos_{i,pair(i)} ]
//
// R3: symmetric triangle with GT=256 row-groups (528 pair-tiles), 512-thread
// blocks, 4 double-buffered 64-col iterations per block (amortizes the A-frag
// setup that killed R2), LDSB=516 (odd dword stride 129 -> conflict-free
// ds_read_b128 fragment reads). exp scale folded into znA so MFMA output is
// the exp2 exponent directly.

#define NROWS 8192
#define NHALF 4096
#define DDIM  256
#define GT    256                          // rows per group
#define NTILES (NROWS / GT)                // 32
#define NBLK  (NTILES * (NTILES + 1) / 2)  // 528 pair-tiles (I <= J)
#define BN    64                           // staged cols per iteration
#define ITERS (GT / BN)                    // 4
#define LDSB  516                          // 512+4: stride 129 dwords (odd) -> no bank conflicts

typedef __bf16 bf16;
typedef __bf16 bf16x4 __attribute__((ext_vector_type(4)));
typedef __bf16 bf16x8 __attribute__((ext_vector_type(8)));
typedef float  f32x4  __attribute__((ext_vector_type(4)));

__constant__ const float kC   = 2.8853900817779268f;  // 2*log2(e)
__constant__ const float kLn2 = 0.6931471805599453f;

// ---------------- k1: normalize ----------------
__global__ void k_normalize(const float* __restrict__ z1, const float* __restrict__ z2,
                            bf16* __restrict__ znA, bf16* __restrict__ znB,
                            float* __restrict__ rowsum, float* __restrict__ out) {
  const int wave = threadIdx.x >> 6, lane = threadIdx.x & 63;
  const int row = blockIdx.x * 4 + wave;
  const float* src = (row < NHALF) ? z1 + (size_t)row * DDIM
                                   : z2 + (size_t)(row - NHALF) * DDIM;
  f32x4 v = *(const f32x4*)(src + lane * 4);
  float ss = v.x * v.x + v.y * v.y + v.z * v.z + v.w * v.w;
#pragma unroll
  for (int off = 1; off < 64; off <<= 1) ss += __shfl_xor(ss, off);
  const float inv  = 1.0f / fmaxf(sqrtf(ss), 1e-8f);
  const float invc = inv * kC;
  bf16x4 oa, ob;
  oa.x = (bf16)(v.x * invc); oa.y = (bf16)(v.y * invc);
  oa.z = (bf16)(v.z * invc); oa.w = (bf16)(v.w * invc);
  ob.x = (bf16)(v.x * inv);  ob.y = (bf16)(v.y * inv);
  ob.z = (bf16)(v.z * inv);  ob.w = (bf16)(v.w * inv);
  *(bf16x4*)(znA + (size_t)row * DDIM + lane * 4) = oa;
  *(bf16x4*)(znB + (size_t)row * DDIM + lane * 4) = ob;
  if (lane == 0) rowsum[row] = 0.0f;
  if (blockIdx.x == 0 && threadIdx.x == 0) out[0] = 0.0f;
}

// ---------------- k2: symmetric Gram row-sums of exp ----------------
// 512 threads = 8 waves; wave owns 32 rows of group I (A in 64 VGPRs).
// 4 iterations of BN=64 cols of group J staged in LDS (double-buffered).
// Row-side sums -> rowsum[I rows]; col-side (LDS-accumulated, off-diag only)
// -> rowsum[J rows].
__global__ __launch_bounds__(512, 4) void k_gram(const bf16* __restrict__ znA,
                                                 const bf16* __restrict__ znB,
                                                 float* __restrict__ rowsum) {
  __shared__ __align__(16) unsigned char lds[2][BN * LDSB];
  __shared__ float colsum[GT];
  const int tid  = threadIdx.x;
  const int wave = tid >> 6, lane = tid & 63;
  const int quad = lane >> 4, l15 = lane & 15;

  // blockIdx -> unordered pair (I, J), I <= J (row-major over triangle:
  // consecutive blocks share I -> co-resident blocks reuse A rows in L2)
  int p = blockIdx.x, I = 0;
  while (p >= NTILES - I) { p -= NTILES - I; ++I; }
  const int J = I + p;
  const bool diag = (I == J);
  const int c0 = J * GT;

  if (tid < GT) colsum[tid] = 0.0f;

  // A fragments: rows I*256 + wave*32 + s*16 + l15; K=256 -> 8 chunks of 32.
  bf16x8 a[2][8];
#pragma unroll
  for (int s = 0; s < 2; ++s) {
    const int row = I * GT + wave * 32 + s * 16 + l15;
    const bf16x8* ap = (const bf16x8*)(znA + (size_t)row * DDIM);
#pragma unroll
    for (int k = 0; k < 8; ++k) a[s][k] = ap[k * 4 + quad];  // elems k*32 + quad*8
  }

  // staging: 512 threads x 4 chunks of 16B = 64 rows x 512B
  const int tr = tid >> 3, tc = tid & 7;
  uint4 g[4];
  {
    const unsigned char* gp = (const unsigned char*)(znB + (size_t)(c0 + tr) * DDIM);
#pragma unroll
    for (int j = 0; j < 4; ++j) g[j] = *(const uint4*)(gp + (tc + 8 * j) * 16);
  }
#pragma unroll
  for (int j = 0; j < 4; ++j)
    *(uint4*)(&lds[0][tr * LDSB + (tc + 8 * j) * 16]) = g[j];

  float sum[2][4] = {{0.f, 0.f, 0.f, 0.f}, {0.f, 0.f, 0.f, 0.f}};
  const f32x4 zero4 = {0.f, 0.f, 0.f, 0.f};

  for (int it = 0; it < ITERS; ++it) {
    __syncthreads();  // staged buf (it&1) ready; prior reads of other buf done
    const int cur = it & 1;
    if (it + 1 < ITERS) {
      const unsigned char* gp =
          (const unsigned char*)(znB + (size_t)(c0 + (it + 1) * BN + tr) * DDIM);
#pragma unroll
      for (int j = 0; j < 4; ++j) g[j] = *(const uint4*)(gp + (tc + 8 * j) * 16);
    }

    f32x4 acc[2][4];
#pragma unroll
    for (int s = 0; s < 2; ++s)
#pragma unroll
      for (int cs = 0; cs < 4; ++cs) acc[s][cs] = zero4;

#pragma unroll
    for (int k = 0; k < 8; ++k) {
      bf16x8 b[4];
#pragma unroll
      for (int cs = 0; cs < 4; ++cs)
        b[cs] = *(const bf16x8*)(&lds[cur][(cs * 16 + l15) * LDSB + k * 64 + quad * 16]);
#pragma unroll
      for (int s = 0; s < 2; ++s)
#pragma unroll
        for (int cs = 0; cs < 4; ++cs)
          acc[s][cs] = __builtin_amdgcn_mfma_f32_16x16x32_bf16(a[s][k], b[cs], acc[s][cs], 0, 0, 0);
    }

    if (it + 1 < ITERS) {
#pragma unroll
      for (int j = 0; j < 4; ++j)
        *(uint4*)(&lds[cur ^ 1][tr * LDSB + (tc + 8 * j) * 16]) = g[j];
    }

    // epilogue: MFMA output IS the exp2 exponent (scale folded into znA)
#pragma unroll
    for (int cs = 0; cs < 4; ++cs) {
      float cp = 0.0f;
#pragma unroll
      for (int s = 0; s < 2; ++s)
#pragma unroll
        for (int r = 0; r < 4; ++r) {
          const float v = __builtin_amdgcn_exp2f(acc[s][cs][r]);
          sum[s][r] += v;  // row-side running sum (row fixed per lane: quad*4+r)
          cp += v;
        }
      if (!diag) {  // col-side: reduce over the wave's 32 rows (4 quads)
        cp += __shfl_xor(cp, 16);
        cp += __shfl_xor(cp, 32);
        if (lane < 16) atomicAdd(&colsum[it * BN + cs * 16 + l15], cp);
      }
    }
  }

  // row flush: C layout (m89): col = l15, row = quad*4 + r -> reduce over l15
#pragma unroll
  for (int s = 0; s < 2; ++s)
#pragma unroll
    for (int r = 0; r < 4; ++r) {
      float v = sum[s][r];
      v += __shfl_xor(v, 1); v += __shfl_xor(v, 2);
      v += __shfl_xor(v, 4); v += __shfl_xor(v, 8);
      if (l15 == 0)
        atomicAdd(&rowsum[I * GT + wave * 32 + s * 16 + quad * 4 + r], v);
    }

  // col flush
  __syncthreads();
  if (!diag && tid < GT) atomicAdd(&rowsum[c0 + tid], colsum[tid]);
}

// ---------------- k3: finalize (pairs) ----------------
__device__ __forceinline__ float dot4(bf16x4 a, bf16x4 b) {
  return (float)a.x * (float)b.x + (float)a.y * (float)b.y +
         (float)a.z * (float)b.z + (float)a.w * (float)b.w;
}

__global__ void k_finalize(const bf16* __restrict__ znA, const bf16* __restrict__ znB,
                           const float* __restrict__ rowsum, float* __restrict__ out) {
  const int wave = threadIdx.x >> 6, lane = threadIdx.x & 63;
  const int gw = blockIdx.x * 4 + wave;  // 0..255, each handles 16 pairs
  float acc = 0.0f;
  for (int t = 0; t < 16; ++t) {
    const int q = gw * 16 + t, pq = q + NHALF;
    bf16x4 aq = *(const bf16x4*)(znA + (size_t)q  * DDIM + lane * 4);
    bf16x4 bq = *(const bf16x4*)(znB + (size_t)q  * DDIM + lane * 4);
    bf16x4 ap = *(const bf16x4*)(znA + (size_t)pq * DDIM + lane * 4);
    bf16x4 bp = *(const bf16x4*)(znB + (size_t)pq * DDIM + lane * 4);
    float dqq = dot4(aq, bq);   // exp2 exponent of Gram diagonal, row q
    float dpp = dot4(ap, bp);   // row pq
    float dqp = dot4(aq, bp);   // = 2*log2e*cos(q,pq); sim_pair = dqp*ln2
#pragma unroll
    for (int off = 1; off < 64; off <<= 1) {
      dqq += __shfl_xor(dqq, off);
      dpp += __shfl_xor(dpp, off);
      dqp += __shfl_xor(dqp, off);
    }
    if (lane == 0) {
      const float lseq = __builtin_amdgcn_logf(rowsum[q]  - __builtin_amdgcn_exp2f(dqq)) * kLn2;
      const float lsep = __builtin_amdgcn_logf(rowsum[pq] - __builtin_amdgcn_exp2f(dpp)) * kLn2;
      acc += lseq + lsep - 2.0f * dqp * kLn2;
    }
  }
  __shared__ float ws4[4];
  if (lane == 0) ws4[wave] = acc;
  __syncthreads();
  if (threadIdx.x == 0)
    atomicAdd(out, (ws4[0] + ws4[1] + ws4[2] + ws4[3]) * (1.0f / (float)NROWS));
}

extern "C" void kernel_launch(void* const* d_in, const int* in_sizes, int n_in,
                              void* d_out, int out_size, void* d_ws, size_t ws_size,
                              hipStream_t stream) {
  const float* z1 = (const float*)d_in[0];
  const float* z2 = (const float*)d_in[1];
  unsigned char* ws = (unsigned char*)d_ws;

  // ws: znA bf16[8192*256] | znB bf16[8192*256] | rowsum f32[8192]
  bf16* znA = (bf16*)ws;
  bf16* znB = (bf16*)(ws + (size_t)NROWS * DDIM * sizeof(bf16));
  float* rowsum = (float*)(ws + 2 * (size_t)NROWS * DDIM * sizeof(bf16));
  float* out = (float*)d_out;

  hipLaunchKernelGGL(k_normalize, dim3(NROWS / 4), dim3(256), 0, stream, z1, z2, znA, znB, rowsum, out);
  hipLaunchKernelGGL(k_gram, dim3(NBLK), dim3(512), 0, stream, znA, znB, rowsum);
  hipLaunchKernelGGL(k_finalize, dim3(64), dim3(256), 0, stream, znA, znB, rowsum, out);
}

// Round 4
// 116.987 us; speedup vs baseline: 1.4843x; 1.4843x over previous
//
#include <hip/hip_runtime.h>
#include <hip/hip_bf16.h>

// NT-Xent loss, N=4096, D=256, fp32 in, fp32 scalar out.
// loss = mean_i [ log( sum_{j != i} exp(2*cos_ij) ) - 2*cos_{i,pair(i)} ]
//
// R4: symmetric-triangle Gram, MFMA-bound design.
//  - single zn = bf16(sqrt(2*log2e) * zhat): zn.zn^T IS the exp2 exponent
//  - 512 blocks x 256 thr (4 waves x 64 rows, A in 128 VGPRs), launch_bounds(256,2)
//    -> ~234 unified regs, 2 blocks/CU, NO spills (R3 failure mode)
//  - flat iter list over 2112 triangle col-iters: blocks get 4-5 iters, all
//    512 blocks co-resident in one round (R2 failure mode fixed)
//  - B staged via global_load_lds width=16 into fragment-order LDS chunks
//    (wave-uniform base + lane*16): no staging VGPRs, conflict-free aligned
//    ds_read_b128 with immediate offsets
//  - row-side sums -> atomicAdd rowsum; col-side via LDS colsum, flushed once

#define NROWS 8192
#define NHALF 4096
#define DDIM  256
#define NSTRIP 32     // 256-row strips
#define TILE  256
#define TOTIT 2112    // sum_R 4*(32-R)

typedef __bf16 bf16;
typedef __bf16 bf16x4 __attribute__((ext_vector_type(4)));
typedef __bf16 bf16x8 __attribute__((ext_vector_type(8)));
typedef float  f32x4  __attribute__((ext_vector_type(4)));

__constant__ const float kSqrtC = 1.69864359f;        // sqrt(2*log2(e))
__constant__ const float kLn2   = 0.6931471805599453f;

__device__ __forceinline__ void load_lds16(const bf16* g, bf16* l) {
  __builtin_amdgcn_global_load_lds(
      (const __attribute__((address_space(1))) unsigned int*)g,
      (__attribute__((address_space(3))) unsigned int*)l, 16, 0, 0);
}

// ---------------- k1: normalize ----------------
__global__ void k_normalize(const float* __restrict__ z1, const float* __restrict__ z2,
                            bf16* __restrict__ zn, float* __restrict__ rowsum,
                            float* __restrict__ out) {
  const int wave = threadIdx.x >> 6, lane = threadIdx.x & 63;
  const int row = blockIdx.x * 4 + wave;
  const float* src = (row < NHALF) ? z1 + (size_t)row * DDIM
                                   : z2 + (size_t)(row - NHALF) * DDIM;
  f32x4 v = *(const f32x4*)(src + lane * 4);
  float ss = v.x * v.x + v.y * v.y + v.z * v.z + v.w * v.w;
#pragma unroll
  for (int off = 1; off < 64; off <<= 1) ss += __shfl_xor(ss, off);
  const float inv = kSqrtC / fmaxf(sqrtf(ss), 1e-8f);
  bf16x4 o;
  o.x = (bf16)(v.x * inv); o.y = (bf16)(v.y * inv);
  o.z = (bf16)(v.z * inv); o.w = (bf16)(v.w * inv);
  *(bf16x4*)(zn + (size_t)row * DDIM + lane * 4) = o;
  if (lane == 0) rowsum[row] = 0.0f;
  if (blockIdx.x == 0 && threadIdx.x == 0) out[0] = 0.0f;
}

// ---------------- k2: symmetric Gram row-sums of exp2 ----------------
__global__ __launch_bounds__(256, 2) void k_gram(const bf16* __restrict__ zn,
                                                 float* __restrict__ rowsum) {
  // fragment-order staging: chunk (k*4+cs) = 1024B = one wave-fragment set
  __shared__ __align__(16) bf16 bstage[2][32 * 512];  // 2 x 32 KB
  __shared__ float colsum[320];                       // up to 5 iters x 64 cols
  const int tid  = threadIdx.x;
  const int wave = tid >> 6, lane = tid & 63;
  const int quad = lane >> 4, l15 = lane & 15;

  // flat iter assignment: 2112 = 64*5 + 448*4
  int t0, cnt;
  if (blockIdx.x < 64) { t0 = blockIdx.x * 5; cnt = 5; }
  else                 { t0 = 320 + ((int)blockIdx.x - 64) * 4; cnt = 4; }

  // locate strip R / iter-within-strip for t0
  int R = 0, rem = t0;
  while (rem >= 4 * (NSTRIP - R)) { rem -= 4 * (NSTRIP - R); ++R; }
  int cloc = rem;  // col-iter within strip; colbase = R*256 + cloc*64; diag tile iff cloc<4

  for (int i = tid; i < 320; i += 256) colsum[i] = 0.0f;

  // A fragments: wave owns rows R*256 + wave*64 + s*16 + l15, K=256 in 8 chunks
  bf16x8 a[4][8];
  auto loadA = [&](int Rv) {
#pragma unroll
    for (int s = 0; s < 4; ++s) {
      const int row = Rv * TILE + wave * 64 + s * 16 + l15;
      const bf16x8* ap = (const bf16x8*)(zn + (size_t)row * DDIM);
#pragma unroll
      for (int k = 0; k < 8; ++k) a[s][k] = ap[k * 4 + quad];  // elems k*32 + quad*8
    }
  };
  loadA(R);

  float sum[4][4];
#pragma unroll
  for (int s = 0; s < 4; ++s)
#pragma unroll
    for (int r = 0; r < 4; ++r) sum[s][r] = 0.0f;

  auto flush_rows = [&]() {
#pragma unroll
    for (int s = 0; s < 4; ++s)
#pragma unroll
      for (int r = 0; r < 4; ++r) {
        float v = sum[s][r];
        v += __shfl_xor(v, 1); v += __shfl_xor(v, 2);
        v += __shfl_xor(v, 4); v += __shfl_xor(v, 8);
        if (l15 == 0)
          atomicAdd(&rowsum[R * TILE + wave * 64 + s * 16 + quad * 4 + r], v);
        sum[s][r] = 0.0f;
      }
  };

  // stage 64 cols (fragment-order) for one iter: wave handles 8 chunks
  auto stage = [&](int buf, int colbase) {
#pragma unroll
    for (int c = 0; c < 8; ++c) {
      const int chunk = wave * 8 + c;          // 0..31
      const int kk = chunk >> 2, cs = chunk & 3;
      const bf16* g = zn + (size_t)(colbase + cs * 16 + l15) * DDIM + kk * 32 + quad * 8;
      load_lds16(g, &bstage[buf][chunk * 512]);  // lane*16B appended by HW
    }
  };
  stage(0, R * TILE + cloc * 64);

  const f32x4 zero4 = {0.f, 0.f, 0.f, 0.f};

  for (int tl = 0; tl < cnt; ++tl) {
    __syncthreads();  // drains this wave's global_load_lds (vmcnt) + buf swap
    const int cur = tl & 1;
    if (tl + 1 < cnt) {  // prefetch next iter's cols into other buffer
      int Rn = R, cn = cloc + 1;
      if (cn == 4 * (NSTRIP - Rn)) { cn = 0; ++Rn; }
      stage(cur ^ 1, Rn * TILE + cn * 64);
    }
    const bool dt = (cloc < 4);  // diagonal-tile iter: skip col-side

    f32x4 acc[4][4];
#pragma unroll
    for (int k = 0; k < 8; ++k) {
      bf16x8 b[4];
#pragma unroll
      for (int cs = 0; cs < 4; ++cs)
        b[cs] = *(const bf16x8*)(&bstage[cur][(k * 4 + cs) * 512 + lane * 8]);
#pragma unroll
      for (int s = 0; s < 4; ++s)
#pragma unroll
        for (int cs = 0; cs < 4; ++cs)
          acc[s][cs] = __builtin_amdgcn_mfma_f32_16x16x32_bf16(
              a[s][k], b[cs], k ? acc[s][cs] : zero4, 0, 0, 0);
    }

    // epilogue: MFMA output IS the exp2 exponent
#pragma unroll
    for (int cs = 0; cs < 4; ++cs) {
      float cp = 0.0f;
#pragma unroll
      for (int s = 0; s < 4; ++s)
#pragma unroll
        for (int r = 0; r < 4; ++r) {
          const float v = __builtin_amdgcn_exp2f(acc[s][cs][r]);
          sum[s][r] += v;  // row quad*4+r (C layout m89: row=quad*4+reg, col=l15)
          cp += v;
        }
      if (!dt) {  // col-side: reduce this wave's 64 rows (over s,r done; over quad:)
        cp += __shfl_xor(cp, 16);
        cp += __shfl_xor(cp, 32);
        if (lane < 16) atomicAdd(&colsum[tl * 64 + cs * 16 + l15], cp);
      }
    }

    // advance iterator; on strip change flush row sums & reload A
    ++cloc;
    if (cloc == 4 * (NSTRIP - R) && tl + 1 < cnt) {
      flush_rows();
      ++R; cloc = 0;
      loadA(R);
    }
  }
  flush_rows();

  __syncthreads();
  // col flush: recompute global col for each local iter (diag iters hold 0)
  for (int idx = tid; idx < cnt * 64; idx += 256) {
    const int tloc = idx >> 6;
    int Rv = 0, r2 = t0 + tloc;
    while (r2 >= 4 * (NSTRIP - Rv)) { r2 -= 4 * (NSTRIP - Rv); ++Rv; }
    const int col = Rv * TILE + r2 * 64 + (idx & 63);
    atomicAdd(&rowsum[col], colsum[idx]);
  }
}

// ---------------- k3: finalize (pairs) ----------------
__device__ __forceinline__ float dot4(bf16x4 a, bf16x4 b) {
  return (float)a.x * (float)b.x + (float)a.y * (float)b.y +
         (float)a.z * (float)b.z + (float)a.w * (float)b.w;
}

__global__ void k_finalize(const bf16* __restrict__ zn, const float* __restrict__ rowsum,
                           float* __restrict__ out) {
  const int wave = threadIdx.x >> 6, lane = threadIdx.x & 63;
  const int gw = blockIdx.x * 4 + wave;  // 0..255, 16 pairs each
  float acc = 0.0f;
  for (int t = 0; t < 16; ++t) {
    const int q = gw * 16 + t, pq = q + NHALF;
    bf16x4 zq = *(const bf16x4*)(zn + (size_t)q  * DDIM + lane * 4);
    bf16x4 zp = *(const bf16x4*)(zn + (size_t)pq * DDIM + lane * 4);
    float dqq = dot4(zq, zq);  // exp2 exponent of Gram diagonal, row q
    float dpp = dot4(zp, zp);  // row pq
    float dqp = dot4(zq, zp);  // = 2*log2e*cos(q,pq); sim = dqp*ln2
#pragma unroll
    for (int off = 1; off < 64; off <<= 1) {
      dqq += __shfl_xor(dqq, off);
      dpp += __shfl_xor(dpp, off);
      dqp += __shfl_xor(dqp, off);
    }
    if (lane == 0) {
      const float lseq = __builtin_amdgcn_logf(rowsum[q]  - __builtin_amdgcn_exp2f(dqq)) * kLn2;
      const float lsep = __builtin_amdgcn_logf(rowsum[pq] - __builtin_amdgcn_exp2f(dpp)) * kLn2;
      acc += lseq + lsep - 2.0f * dqp * kLn2;
    }
  }
  __shared__ float ws4[4];
  if (lane == 0) ws4[wave] = acc;
  __syncthreads();
  if (threadIdx.x == 0)
    atomicAdd(out, (ws4[0] + ws4[1] + ws4[2] + ws4[3]) * (1.0f / (float)NROWS));
}

extern "C" void kernel_launch(void* const* d_in, const int* in_sizes, int n_in,
                              void* d_out, int out_size, void* d_ws, size_t ws_size,
                              hipStream_t stream) {
  const float* z1 = (const float*)d_in[0];
  const float* z2 = (const float*)d_in[1];
  unsigned char* ws = (unsigned char*)d_ws;

  // ws: zn bf16[8192*256] (4 MB) | rowsum f32[8192]
  bf16* zn = (bf16*)ws;
  float* rowsum = (float*)(ws + (size_t)NROWS * DDIM * sizeof(bf16));
  float* out = (float*)d_out;

  hipLaunchKernelGGL(k_normalize, dim3(NROWS / 4), dim3(256), 0, stream, z1, z2, zn, rowsum, out);
  hipLaunchKernelGGL(k_gram, dim3(512), dim3(256), 0, stream, zn, rowsum);
  hipLaunchKernelGGL(k_finalize, dim3(64), dim3(256), 0, stream, zn, rowsum, out);
}

// Round 5
// 115.078 us; speedup vs baseline: 1.5089x; 1.0166x over previous
//
#include <hip/hip_runtime.h>
#include <hip/hip_bf16.h>

// NT-Xent loss, N=4096, D=256, fp32 in, fp32 scalar out.
// loss = mean_i [ log( sum_{j != i} exp(2*cos_ij) ) - 2*cos_{i,pair(i)} ]
//
// R5: symmetric-triangle Gram, spill-proof configuration.
//  - zn = bf16(sqrt(2*log2e) * zhat): zn.zn^T IS the exp2 exponent
//  - 512 blocks x 512 thr (8 waves x 32 rows; a[2][8]=64 regs -> ~170 total,
//    launch_bounds(512,2) cap 256: NO spills, 2-3 blocks/CU)
//  - single 32 KB fragment-order B buffer, m97-style 2-barrier loop,
//    global_load_lds width=16 (no staging VGPRs, conflict-free ds_read_b128)
//  - flat iter list over 2112 triangle col-iters (R4-verified iterator):
//    row-side sums in regs -> atomicAdd on strip change; col-side via LDS
//    colsum, flushed once at end (skipped on diagonal tiles)

#define NROWS 8192
#define NHALF 4096
#define DDIM  256
#define NSTRIP 32     // 256-row strips
#define TILE  256

typedef __bf16 bf16;
typedef __bf16 bf16x4 __attribute__((ext_vector_type(4)));
typedef __bf16 bf16x8 __attribute__((ext_vector_type(8)));
typedef float  f32x4  __attribute__((ext_vector_type(4)));

__constant__ const float kSqrtC = 1.69864359f;        // sqrt(2*log2(e))
__constant__ const float kLn2   = 0.6931471805599453f;

__device__ __forceinline__ void load_lds16(const bf16* g, bf16* l) {
  __builtin_amdgcn_global_load_lds(
      (const __attribute__((address_space(1))) unsigned int*)g,
      (__attribute__((address_space(3))) unsigned int*)l, 16, 0, 0);
}

// ---------------- k1: normalize ----------------
__global__ void k_normalize(const float* __restrict__ z1, const float* __restrict__ z2,
                            bf16* __restrict__ zn, float* __restrict__ rowsum,
                            float* __restrict__ out) {
  const int wave = threadIdx.x >> 6, lane = threadIdx.x & 63;
  const int row = blockIdx.x * 4 + wave;
  const float* src = (row < NHALF) ? z1 + (size_t)row * DDIM
                                   : z2 + (size_t)(row - NHALF) * DDIM;
  f32x4 v = *(const f32x4*)(src + lane * 4);
  float ss = v.x * v.x + v.y * v.y + v.z * v.z + v.w * v.w;
#pragma unroll
  for (int off = 1; off < 64; off <<= 1) ss += __shfl_xor(ss, off);
  const float inv = kSqrtC / fmaxf(sqrtf(ss), 1e-8f);
  bf16x4 o;
  o.x = (bf16)(v.x * inv); o.y = (bf16)(v.y * inv);
  o.z = (bf16)(v.z * inv); o.w = (bf16)(v.w * inv);
  *(bf16x4*)(zn + (size_t)row * DDIM + lane * 4) = o;
  if (lane == 0) rowsum[row] = 0.0f;
  if (blockIdx.x == 0 && threadIdx.x == 0) out[0] = 0.0f;
}

// ---------------- k2: symmetric Gram row-sums of exp2 ----------------
__global__ __launch_bounds__(512, 2) void k_gram(const bf16* __restrict__ zn,
                                                 float* __restrict__ rowsum) {
  // fragment-order staging: chunk (k*4+cs) = 1024 B = one wave-fragment set
  __shared__ __align__(16) bf16 bstage[32 * 512];  // 32 KB, single buffer
  __shared__ float colsum[320];                    // up to 5 iters x 64 cols
  const int tid  = threadIdx.x;
  const int wave = tid >> 6, lane = tid & 63;
  const int quad = lane >> 4, l15 = lane & 15;

  // flat iter assignment over 2112 = 64*5 + 448*4 (all 512 blocks co-resident)
  int t0, cnt;
  if (blockIdx.x < 64) { t0 = blockIdx.x * 5; cnt = 5; }
  else                 { t0 = 320 + ((int)blockIdx.x - 64) * 4; cnt = 4; }

  // locate strip R / col-iter-within-strip for t0
  int R = 0, rem = t0;
  while (rem >= 4 * (NSTRIP - R)) { rem -= 4 * (NSTRIP - R); ++R; }
  int cloc = rem;  // colbase = R*256 + cloc*64; diagonal tile iff cloc < 4

  for (int i = tid; i < 320; i += 512) colsum[i] = 0.0f;

  // A fragments: wave owns rows R*256 + wave*32 + s*16 + l15; K=256 in 8 chunks
  bf16x8 a[2][8];
  auto loadA = [&](int Rv) {
#pragma unroll
    for (int s = 0; s < 2; ++s) {
      const int row = Rv * TILE + wave * 32 + s * 16 + l15;
      const bf16x8* ap = (const bf16x8*)(zn + (size_t)row * DDIM);
#pragma unroll
      for (int k = 0; k < 8; ++k) a[s][k] = ap[k * 4 + quad];  // elems k*32 + quad*8
    }
  };
  loadA(R);

  float sum[2][4] = {{0.f, 0.f, 0.f, 0.f}, {0.f, 0.f, 0.f, 0.f}};

  auto flush_rows = [&]() {
#pragma unroll
    for (int s = 0; s < 2; ++s)
#pragma unroll
      for (int r = 0; r < 4; ++r) {
        float v = sum[s][r];
        v += __shfl_xor(v, 1); v += __shfl_xor(v, 2);
        v += __shfl_xor(v, 4); v += __shfl_xor(v, 8);
        if (l15 == 0)
          atomicAdd(&rowsum[R * TILE + wave * 32 + s * 16 + quad * 4 + r], v);
        sum[s][r] = 0.0f;
      }
  };

  const f32x4 zero4 = {0.f, 0.f, 0.f, 0.f};

  for (int tl = 0; tl < cnt; ++tl) {
    const int colbase = R * TILE + cloc * 64;
    const bool dt = (cloc < 4);  // diagonal tile: skip col-side

    __syncthreads();  // all waves done reading bstage from previous iter
    // stage 64 cols fragment-order: wave handles 4 of 32 1-KB chunks
#pragma unroll
    for (int c = 0; c < 4; ++c) {
      const int chunk = wave * 4 + c;           // 0..31
      const int kk = chunk >> 2, cs = chunk & 3;
      const bf16* g = zn + (size_t)(colbase + cs * 16 + l15) * DDIM + kk * 32 + quad * 8;
      load_lds16(g, &bstage[chunk * 512]);      // + lane*16B by HW
    }
    __syncthreads();  // vmcnt(0) drain before barrier -> buffer fully staged

    f32x4 acc[2][4];
#pragma unroll
    for (int k = 0; k < 8; ++k) {
      bf16x8 b[4];
#pragma unroll
      for (int cs = 0; cs < 4; ++cs)
        b[cs] = *(const bf16x8*)(&bstage[(k * 4 + cs) * 512 + lane * 8]);
#pragma unroll
      for (int s = 0; s < 2; ++s)
#pragma unroll
        for (int cs = 0; cs < 4; ++cs)
          acc[s][cs] = __builtin_amdgcn_mfma_f32_16x16x32_bf16(
              a[s][k], b[cs], k ? acc[s][cs] : zero4, 0, 0, 0);
    }

    // epilogue: MFMA output IS the exp2 exponent
#pragma unroll
    for (int cs = 0; cs < 4; ++cs) {
      float cp = 0.0f;
#pragma unroll
      for (int s = 0; s < 2; ++s)
#pragma unroll
        for (int r = 0; r < 4; ++r) {
          const float v = __builtin_amdgcn_exp2f(acc[s][cs][r]);
          sum[s][r] += v;  // row-side (C layout m89: row=quad*4+reg, col=l15)
          cp += v;
        }
      if (!dt) {  // col-side: reduce the wave's 32 rows (quads), then LDS-acc
        cp += __shfl_xor(cp, 16);
        cp += __shfl_xor(cp, 32);
        if (lane < 16) atomicAdd(&colsum[tl * 64 + cs * 16 + l15], cp);
      }
    }

    // advance iterator; on strip change flush row sums & reload A
    ++cloc;
    if (cloc == 4 * (NSTRIP - R) && tl + 1 < cnt) {
      flush_rows();
      ++R; cloc = 0;
      loadA(R);
    }
  }
  flush_rows();

  __syncthreads();
  // col flush: recompute global col per local iter (diag iters hold 0)
  for (int idx = tid; idx < cnt * 64; idx += 512) {
    const int tloc = idx >> 6;
    int Rv = 0, r2 = t0 + tloc;
    while (r2 >= 4 * (NSTRIP - Rv)) { r2 -= 4 * (NSTRIP - Rv); ++Rv; }
    const int col = Rv * TILE + r2 * 64 + (idx & 63);
    atomicAdd(&rowsum[col], colsum[idx]);
  }
}

// ---------------- k3: finalize (pairs) ----------------
__device__ __forceinline__ float dot4(bf16x4 a, bf16x4 b) {
  return (float)a.x * (float)b.x + (float)a.y * (float)b.y +
         (float)a.z * (float)b.z + (float)a.w * (float)b.w;
}

__global__ void k_finalize(const bf16* __restrict__ zn, const float* __restrict__ rowsum,
                           float* __restrict__ out) {
  const int wave = threadIdx.x >> 6, lane = threadIdx.x & 63;
  const int gw = blockIdx.x * 4 + wave;  // 0..255, 16 pairs each
  float acc = 0.0f;
  for (int t = 0; t < 16; ++t) {
    const int q = gw * 16 + t, pq = q + NHALF;
    bf16x4 zq = *(const bf16x4*)(zn + (size_t)q  * DDIM + lane * 4);
    bf16x4 zp = *(const bf16x4*)(zn + (size_t)pq * DDIM + lane * 4);
    float dqq = dot4(zq, zq);  // exp2 exponent of Gram diagonal, row q
    float dpp = dot4(zp, zp);  // row pq
    float dqp = dot4(zq, zp);  // = 2*log2e*cos(q,pq); sim = dqp*ln2
#pragma unroll
    for (int off = 1; off < 64; off <<= 1) {
      dqq += __shfl_xor(dqq, off);
      dpp += __shfl_xor(dpp, off);
      dqp += __shfl_xor(dqp, off);
    }
    if (lane == 0) {
      const float lseq = __builtin_amdgcn_logf(rowsum[q]  - __builtin_amdgcn_exp2f(dqq)) * kLn2;
      const float lsep = __builtin_amdgcn_logf(rowsum[pq] - __builtin_amdgcn_exp2f(dpp)) * kLn2;
      acc += lseq + lsep - 2.0f * dqp * kLn2;
    }
  }
  __shared__ float ws4[4];
  if (lane == 0) ws4[wave] = acc;
  __syncthreads();
  if (threadIdx.x == 0)
    atomicAdd(out, (ws4[0] + ws4[1] + ws4[2] + ws4[3]) * (1.0f / (float)NROWS));
}

extern "C" void kernel_launch(void* const* d_in, const int* in_sizes, int n_in,
                              void* d_out, int out_size, void* d_ws, size_t ws_size,
                              hipStream_t stream) {
  const float* z1 = (const float*)d_in[0];
  const float* z2 = (const float*)d_in[1];
  unsigned char* ws = (unsigned char*)d_ws;

  // ws: zn bf16[8192*256] (4 MB) | rowsum f32[8192]
  bf16* zn = (bf16*)ws;
  float* rowsum = (float*)(ws + (size_t)NROWS * DDIM * sizeof(bf16));
  float* out = (float*)d_out;

  hipLaunchKernelGGL(k_normalize, dim3(NROWS / 4), dim3(256), 0, stream, z1, z2, zn, rowsum, out);
  hipLaunchKernelGGL(k_gram, dim3(512), dim3(512), 0, stream, zn, rowsum);
  hipLaunchKernelGGL(k_finalize, dim3(64), dim3(256), 0, stream, zn, rowsum, out);
}